// Round 3
// baseline (20182.745 us; speedup 1.0000x reference)
//
#include <hip/hip_runtime.h>
#include <math.h>

#define TT 2048
#define NB 64
#define EE 256
#define HH 256
#define NGRP 16   // batch groups (4 batches each)
#define PJ 16     // j-partitions (WGs) per group
#define JW 16     // j per WG
#define ROWS 64   // gate-rows per WG (4 gates x JW)
#define LDW 260   // padded LDS row stride in floats

__device__ __forceinline__ float sigf(float x) { return 1.f / (1.f + expf(-x)); }

// Persistent grouped LSTM: 256 WGs = 16 batch-groups x 16 j-slices, 1 WG/CU.
// hbuf is DOUBLE-BUFFERED: step t writes buf[t&1], reads buf[(t-1)&1].
// The per-step arrival counter then also protects buffer recycling: a writer
// of h_{t+1} (buf (t-1)&1) must first observe cnt[t]==16, and each WG's
// release-add to cnt[t] is program-ordered after its reads of h_{t-1}.
__global__ __launch_bounds__(256, 1)
void lstm_kernel(const int* __restrict__ sent, const float* __restrict__ emb,
                 const float* __restrict__ W_ih, const float* __restrict__ W_hh,
                 const float* __restrict__ b_ih, const float* __restrict__ b_hh,
                 const float* __restrict__ W_z,
                 float* __restrict__ hbuf, unsigned int* __restrict__ cnt,
                 float* __restrict__ part)
{
    __shared__ float Wih_s[ROWS][LDW];
    __shared__ float Whh_s[ROWS][LDW];
    __shared__ float x_s[4][LDW];
    __shared__ float h_s[4][LDW];
    __shared__ float g_s[4][4][JW];   // [gate][b][jj]
    __shared__ float c_s[4][JW];
    __shared__ float p_s[4][JW];
    __shared__ int   tok_s[4];

    const int tid  = threadIdx.x;
    const int grp  = blockIdx.x >> 4;     // 0..15 batch group
    const int jgrp = blockIdx.x & 15;     // 0..15 j-slice
    const int b0   = grp << 2;
    const int j0   = jgrp << 4;

    // thread -> (wave = gate, rr = row-within-gate, bl = local batch)
    const int wv   = tid >> 6;            // 0..3 == gate index
    const int lane = tid & 63;
    const int rr   = lane >> 2;           // 0..15
    const int bl   = lane & 3;            // 0..3
    const int lr   = (wv << 4) + rr;      // 0..63 local row
    const int rg   = wv * HH + j0 + rr;   // global gate row

    // Load W slices once (persistent). Row layout: lr = gate*16 + jj.
    for (int i = tid; i < ROWS * (EE / 4); i += 256) {
        int row = i >> 6;                 // 64 float4 per row
        int c4  = i & 63;
        int gate = row >> 4, jj = row & 15;
        int grow = gate * HH + j0 + jj;
        float4 wih = ((const float4*)(W_ih + (long)grow * EE))[c4];
        float4 whh = ((const float4*)(W_hh + (long)grow * EE))[c4];
        ((float4*)&Wih_s[row][0])[c4] = wih;
        ((float4*)&Whh_s[row][0])[c4] = whh;
    }
    const float bias_r = b_ih[rg] + b_hh[rg];
    float wz_r = 0.f;
    if (tid < 64) {
        c_s[tid >> 4][tid & 15] = 0.f;
        wz_r = W_z[j0 + (tid & 15)];
    }
    __syncthreads();

    unsigned int* mycnt = cnt + grp * TT;

    for (int t = 0; t < TT; ++t) {
        float* hw = hbuf + (t & 1) * (NB * HH);          // write buffer
        const float* hr = hbuf + ((t - 1) & 1) * (NB * HH); // read buffer

        // ---- phase 1: gather x_t, x-projection (no cross-WG dependency) ----
        if (tid < 4) tok_s[tid] = sent[t * NB + b0 + tid];
        __syncthreads();
        {
            int b  = tid >> 6;
            int e4 = tid & 63;
            float4 xv = ((const float4*)(emb + (long)tok_s[b] * EE))[e4];
            ((float4*)&x_s[b][0])[e4] = xv;
        }
        __syncthreads();
        float4 ax0 = make_float4(0.f, 0.f, 0.f, 0.f);
        float4 ax1 = make_float4(0.f, 0.f, 0.f, 0.f);
        #pragma unroll 8
        for (int k8 = 0; k8 < EE / 8; ++k8) {
            float4 w0 = *((const float4*)&Wih_s[lr][k8 * 8]);
            float4 w1 = *((const float4*)&Wih_s[lr][k8 * 8 + 4]);
            float4 x0 = *((const float4*)&x_s[bl][k8 * 8]);
            float4 x1 = *((const float4*)&x_s[bl][k8 * 8 + 4]);
            ax0.x += w0.x * x0.x; ax0.y += w0.y * x0.y;
            ax0.z += w0.z * x0.z; ax0.w += w0.w * x0.w;
            ax1.x += w1.x * x1.x; ax1.y += w1.y * x1.y;
            ax1.z += w1.z * x1.z; ax1.w += w1.w * x1.w;
        }
        float pre = bias_r + (((ax0.x + ax0.y) + (ax0.z + ax0.w)) +
                              ((ax1.x + ax1.y) + (ax1.z + ax1.w)));

        // ---- phase 2: wait for group h_{t-1}, recurrent projection ----
        if (t > 0) {
            if (tid == 0) {
                // ACQUIRE pairs with producers' RELEASE adds.
                while (__hip_atomic_load(&mycnt[t - 1], __ATOMIC_ACQUIRE,
                                         __HIP_MEMORY_SCOPE_AGENT) < (unsigned)PJ) { }
            }
            __syncthreads();   // extends the acquire edge to all threads
            {
                int b = tid >> 6;
                int k = tid & 63;
                const float* src = hr + (b0 + b) * HH;
                #pragma unroll
                for (int i = 0; i < 4; ++i) {
                    h_s[b][k + 64 * i] = __hip_atomic_load(src + k + 64 * i,
                        __ATOMIC_RELAXED, __HIP_MEMORY_SCOPE_AGENT);
                }
            }
            __syncthreads();
            float4 ah0 = make_float4(0.f, 0.f, 0.f, 0.f);
            float4 ah1 = make_float4(0.f, 0.f, 0.f, 0.f);
            #pragma unroll 8
            for (int k8 = 0; k8 < HH / 8; ++k8) {
                float4 w0 = *((const float4*)&Whh_s[lr][k8 * 8]);
                float4 w1 = *((const float4*)&Whh_s[lr][k8 * 8 + 4]);
                float4 h0 = *((const float4*)&h_s[bl][k8 * 8]);
                float4 h1 = *((const float4*)&h_s[bl][k8 * 8 + 4]);
                ah0.x += w0.x * h0.x; ah0.y += w0.y * h0.y;
                ah0.z += w0.z * h0.z; ah0.w += w0.w * h0.w;
                ah1.x += w1.x * h1.x; ah1.y += w1.y * h1.y;
                ah1.z += w1.z * h1.z; ah1.w += w1.w * h1.w;
            }
            pre += (((ah0.x + ah0.y) + (ah0.z + ah0.w)) +
                    ((ah1.x + ah1.y) + (ah1.z + ah1.w)));
        }
        g_s[wv][bl][rr] = pre;
        __syncthreads();

        // ---- phase 3: gates + state update (64 threads own (b,jj)) ----
        if (tid < 64) {
            int b = tid >> 4, jj = tid & 15;
            float gi = g_s[0][b][jj], gf = g_s[1][b][jj];
            float gg = g_s[2][b][jj], go = g_s[3][b][jj];
            float c  = c_s[b][jj];
            float cn = sigf(gf) * c + sigf(gi) * tanhf(gg);
            float hn = sigf(go) * tanhf(cn);
            c_s[b][jj] = cn;
            p_s[b][jj] = hn * wz_r;
            __hip_atomic_store(hw + (b0 + b) * HH + j0 + jj, hn,
                               __ATOMIC_RELAXED, __HIP_MEMORY_SCOPE_AGENT);
        }
        __syncthreads();
        if (tid < 4) {  // deterministic pz partial for this (t, jslice, b)
            float s = 0.f;
            #pragma unroll
            for (int jj = 0; jj < JW; ++jj) s += p_s[tid][jj];
            part[(t * PJ + jgrp) * NB + b0 + tid] = s;
        }
        __syncthreads();   // h stores + p reads complete before release add
        if (tid == 0)
            __hip_atomic_fetch_add(&mycnt[t], 1u, __ATOMIC_RELEASE,
                                   __HIP_MEMORY_SCOPE_AGENT);
    }
}

__global__ void pz_kernel(const float* __restrict__ part,
                          const float* __restrict__ noise,
                          const float* __restrict__ b_z,
                          float* __restrict__ out)
{
    int idx = blockIdx.x * blockDim.x + threadIdx.x;  // t*64 + b
    if (idx >= TT * NB) return;
    int t = idx >> 6, b = idx & 63;
    float s = b_z[0];
    #pragma unroll
    for (int jg = 0; jg < PJ; ++jg) s += part[(t * PJ + jg) * NB + b];
    float pz = 1.f / (1.f + expf(-s));
    out[idx] = pz;
    out[TT * NB + idx] = (noise[idx] < pz) ? 1.f : 0.f;
}

// One block per batch column: stable compaction of tokens where z==1.
__global__ void compact_kernel(const int* __restrict__ sent,
                               const float* __restrict__ zbuf,
                               float* __restrict__ rat,
                               float* __restrict__ zsz)
{
    __shared__ float rat_s[TT];
    __shared__ int scan_s[256];
    int b = blockIdx.x, tid = threadIdx.x;
    int zloc[8];
    int base = tid * 8;
    int c = 0;
    #pragma unroll
    for (int i = 0; i < 8; ++i) {
        zloc[i] = (zbuf[(base + i) * NB + b] != 0.f) ? 1 : 0;
        c += zloc[i];
    }
    scan_s[tid] = c;
    for (int i = tid; i < TT; i += 256) rat_s[i] = 0.f;
    __syncthreads();
    // Hillis-Steele inclusive scan over 256 thread totals
    for (int off = 1; off < 256; off <<= 1) {
        int v = scan_s[tid];
        int add = (tid >= off) ? scan_s[tid - off] : 0;
        __syncthreads();
        scan_s[tid] = v + add;
        __syncthreads();
    }
    int total = scan_s[255];
    int pos = scan_s[tid] - c;  // exclusive prefix
    #pragma unroll
    for (int i = 0; i < 8; ++i) {
        if (zloc[i]) { rat_s[pos] = (float)sent[(base + i) * NB + b]; ++pos; }
    }
    __syncthreads();
    for (int i = tid; i < TT; i += 256) rat[i * NB + b] = rat_s[i];
    if (tid == 0) zsz[b] = (float)total;
}

extern "C" void kernel_launch(void* const* d_in, const int* in_sizes, int n_in,
                              void* d_out, int out_size, void* d_ws, size_t ws_size,
                              hipStream_t stream)
{
    const int*   sent  = (const int*)d_in[0];
    const float* noise = (const float*)d_in[1];
    const float* emb   = (const float*)d_in[2];
    const float* W_ih  = (const float*)d_in[3];
    const float* W_hh  = (const float*)d_in[4];
    const float* b_ih  = (const float*)d_in[5];
    const float* b_hh  = (const float*)d_in[6];
    const float* W_z   = (const float*)d_in[7];
    const float* b_z   = (const float*)d_in[8];
    float* out = (float*)d_out;

    char* ws = (char*)d_ws;
    unsigned int* cnt = (unsigned int*)ws;                  // 16*2048*4   = 128 KB
    float* hbuf = (float*)(ws + 131072);                    // 2*64*256*4  = 128 KB
    float* part = (float*)(ws + 131072 + 131072);           // 2048*16*64*4 = 8 MB

    hipMemsetAsync(cnt, 0, NGRP * TT * sizeof(unsigned int), stream);

    lstm_kernel<<<256, 256, 0, stream>>>(sent, emb, W_ih, W_hh, b_ih, b_hh, W_z,
                                         hbuf, cnt, part);
    pz_kernel<<<(TT * NB) / 256, 256, 0, stream>>>(part, noise, b_z, out);
    compact_kernel<<<NB, 256, 0, stream>>>(sent, out + TT * NB,
                                           out + 2 * TT * NB, out + 3 * TT * NB);
}

// Round 4
// 10124.821 us; speedup vs baseline: 1.9934x; 1.9934x over previous
//
#include <hip/hip_runtime.h>
#include <math.h>

#define TT 2048
#define NB 64
#define EE 256
#define HH 256
#define NGRP 16   // batch groups (4 batches each)
#define PJ 16     // j-partitions (WGs) per group
#define JW 16     // j per WG
#define ROWS 64   // gate-rows per WG (4 gates x JW)
#define LDW 260   // padded LDS row stride in floats

__device__ __forceinline__ float sigf(float x) { return 1.f / (1.f + expf(-x)); }

__device__ __forceinline__ unsigned long long packh(unsigned tag, float v) {
    union { float f; unsigned u; } c; c.f = v;
    return ((unsigned long long)tag << 32) | (unsigned long long)c.u;
}

// Persistent grouped LSTM: 256 WGs = 16 batch-groups x 16 j-slices, 1 WG/CU.
// Handshake: each h value published as one 64-bit relaxed agent atomic
// {tag = t+1, f32 h}. Consumers spin on their own slots until tag matches.
// Double-buffered by step parity; tag disambiguates, skew bound (a writer
// must read all peers' h_{t-1} before publishing h_t) protects recycling.
__global__ __launch_bounds__(256, 1)
void lstm_kernel(const int* __restrict__ sent, const float* __restrict__ emb,
                 const float* __restrict__ W_ih, const float* __restrict__ W_hh,
                 const float* __restrict__ b_ih, const float* __restrict__ b_hh,
                 const float* __restrict__ W_z,
                 unsigned long long* __restrict__ hbuf,
                 float* __restrict__ part)
{
    __shared__ float Wih_s[ROWS][LDW];
    __shared__ float Whh_s[ROWS][LDW];
    __shared__ float x_s[4][LDW];
    __shared__ float h_s[4][LDW];
    __shared__ float g_s[4][4][JW];   // [gate][b][jj]
    __shared__ float c_s[4][JW];
    __shared__ float p_s[4][JW];
    __shared__ int   tok_ns[4];

    const int tid  = threadIdx.x;
    const int grp  = blockIdx.x >> 4;     // 0..15 batch group
    const int jgrp = blockIdx.x & 15;     // 0..15 j-slice
    const int b0   = grp << 2;
    const int j0   = jgrp << 4;

    const int wv   = tid >> 6;            // 0..3 == gate index
    const int lane = tid & 63;
    const int rr   = lane >> 2;           // 0..15
    const int bl   = lane & 3;            // 0..3
    const int lr   = (wv << 4) + rr;      // 0..63 local row
    const int rg   = wv * HH + j0 + rr;   // global gate row

    // Load W slices once (persistent). Row layout: lr = gate*16 + jj.
    for (int i = tid; i < ROWS * (EE / 4); i += 256) {
        int row = i >> 6;                 // 64 float4 per row
        int c4  = i & 63;
        int gate = row >> 4, jj = row & 15;
        int grow = gate * HH + j0 + jj;
        float4 wih = ((const float4*)(W_ih + (long)grow * EE))[c4];
        float4 whh = ((const float4*)(W_hh + (long)grow * EE))[c4];
        ((float4*)&Wih_s[row][0])[c4] = wih;
        ((float4*)&Whh_s[row][0])[c4] = whh;
    }
    const float bias_r = b_ih[rg] + b_hh[rg];
    float wz_r = 0.f;
    if (tid < 64) {
        c_s[tid >> 4][tid & 15] = 0.f;
        wz_r = W_z[j0 + (tid & 15)];
    }
    if (tid < 4) tok_ns[tid] = sent[0 * NB + b0 + tid];
    __syncthreads();
    {   // prologue: x_s for t=0
        int b  = tid >> 6;
        int e4 = tid & 63;
        float4 xv = ((const float4*)(emb + (long)tok_ns[b] * EE))[e4];
        ((float4*)&x_s[b][0])[e4] = xv;
    }
    __syncthreads();

    // consumer mapping: this thread spins on h[(b0+cb)][cj..cj+3]
    const int cb = tid >> 6;
    const int cj = (tid & 63) << 2;

    for (int t = 0; t < TT; ++t) {
        // ---- phase 1: x-projection (x_s ready from previous iteration) ----
        float4 ax0 = make_float4(0.f, 0.f, 0.f, 0.f);
        float4 ax1 = make_float4(0.f, 0.f, 0.f, 0.f);
        #pragma unroll 8
        for (int k8 = 0; k8 < EE / 8; ++k8) {
            float4 w0 = *((const float4*)&Wih_s[lr][k8 * 8]);
            float4 w1 = *((const float4*)&Wih_s[lr][k8 * 8 + 4]);
            float4 x0 = *((const float4*)&x_s[bl][k8 * 8]);
            float4 x1 = *((const float4*)&x_s[bl][k8 * 8 + 4]);
            ax0.x += w0.x * x0.x; ax0.y += w0.y * x0.y;
            ax0.z += w0.z * x0.z; ax0.w += w0.w * x0.w;
            ax1.x += w1.x * x1.x; ax1.y += w1.y * x1.y;
            ax1.z += w1.z * x1.z; ax1.w += w1.w * x1.w;
        }
        float pre = bias_r + (((ax0.x + ax0.y) + (ax0.z + ax0.w)) +
                              ((ax1.x + ax1.y) + (ax1.z + ax1.w)));

        const bool pf = (t + 1 < TT);
        if (tid < 4 && pf) tok_ns[tid] = sent[(t + 1) * NB + b0 + tid];

        // ---- phase 2a: spin on tagged h_{t-1}, fill own h_s slots ----
        if (t > 0) {
            unsigned long long* hp =
                hbuf + ((size_t)(((t - 1) & 1) * NB + b0 + cb)) * HH + cj;
            const unsigned want = (unsigned)t;   // h_{t-1} carries tag t
            unsigned long long v0, v1, v2, v3;
            v0 = __hip_atomic_load(hp + 0, __ATOMIC_RELAXED, __HIP_MEMORY_SCOPE_AGENT);
            v1 = __hip_atomic_load(hp + 1, __ATOMIC_RELAXED, __HIP_MEMORY_SCOPE_AGENT);
            v2 = __hip_atomic_load(hp + 2, __ATOMIC_RELAXED, __HIP_MEMORY_SCOPE_AGENT);
            v3 = __hip_atomic_load(hp + 3, __ATOMIC_RELAXED, __HIP_MEMORY_SCOPE_AGENT);
            while ((unsigned)(v0 >> 32) != want)
                v0 = __hip_atomic_load(hp + 0, __ATOMIC_RELAXED, __HIP_MEMORY_SCOPE_AGENT);
            while ((unsigned)(v1 >> 32) != want)
                v1 = __hip_atomic_load(hp + 1, __ATOMIC_RELAXED, __HIP_MEMORY_SCOPE_AGENT);
            while ((unsigned)(v2 >> 32) != want)
                v2 = __hip_atomic_load(hp + 2, __ATOMIC_RELAXED, __HIP_MEMORY_SCOPE_AGENT);
            while ((unsigned)(v3 >> 32) != want)
                v3 = __hip_atomic_load(hp + 3, __ATOMIC_RELAXED, __HIP_MEMORY_SCOPE_AGENT);
            union { unsigned u; float f; } c0, c1, c2, c3;
            c0.u = (unsigned)v0; c1.u = (unsigned)v1;
            c2.u = (unsigned)v2; c3.u = (unsigned)v3;
            h_s[cb][cj + 0] = c0.f; h_s[cb][cj + 1] = c1.f;
            h_s[cb][cj + 2] = c2.f; h_s[cb][cj + 3] = c3.f;
        }
        __syncthreads();   // B1: h_s ready, tok_ns ready, x_s reads done

        // prefetch next emb row into registers (latency hidden behind hacc)
        float4 xv;
        if (pf) {
            int b  = tid >> 6;
            int e4 = tid & 63;
            xv = ((const float4*)(emb + (long)tok_ns[b] * EE))[e4];
        }

        // ---- phase 2b: recurrent projection ----
        if (t > 0) {
            float4 ah0 = make_float4(0.f, 0.f, 0.f, 0.f);
            float4 ah1 = make_float4(0.f, 0.f, 0.f, 0.f);
            #pragma unroll 8
            for (int k8 = 0; k8 < HH / 8; ++k8) {
                float4 w0 = *((const float4*)&Whh_s[lr][k8 * 8]);
                float4 w1 = *((const float4*)&Whh_s[lr][k8 * 8 + 4]);
                float4 h0 = *((const float4*)&h_s[bl][k8 * 8]);
                float4 h1 = *((const float4*)&h_s[bl][k8 * 8 + 4]);
                ah0.x += w0.x * h0.x; ah0.y += w0.y * h0.y;
                ah0.z += w0.z * h0.z; ah0.w += w0.w * h0.w;
                ah1.x += w1.x * h1.x; ah1.y += w1.y * h1.y;
                ah1.z += w1.z * h1.z; ah1.w += w1.w * h1.w;
            }
            pre += (((ah0.x + ah0.y) + (ah0.z + ah0.w)) +
                    ((ah1.x + ah1.y) + (ah1.z + ah1.w)));
        }
        g_s[wv][bl][rr] = pre;
        __syncthreads();   // B2: g_s ready

        // ---- phase 3: gates + state update + tagged publish ----
        if (tid < 64) {
            int b = tid >> 4, jj = tid & 15;
            float gi = g_s[0][b][jj], gf = g_s[1][b][jj];
            float gg = g_s[2][b][jj], go = g_s[3][b][jj];
            float c  = c_s[b][jj];
            float cn = sigf(gf) * c + sigf(gi) * tanhf(gg);
            float hn = sigf(go) * tanhf(cn);
            c_s[b][jj] = cn;
            p_s[b][jj] = hn * wz_r;
            __hip_atomic_store(
                hbuf + ((size_t)((t & 1) * NB + b0 + b)) * HH + j0 + jj,
                packh((unsigned)(t + 1), hn),
                __ATOMIC_RELAXED, __HIP_MEMORY_SCOPE_AGENT);
        }
        __syncthreads();   // B3: p_s ready; x_s safe to overwrite

        if (tid < 4) {     // deterministic pz partial for this (t, jslice, b)
            float s = 0.f;
            #pragma unroll
            for (int jj = 0; jj < JW; ++jj) s += p_s[tid][jj];
            part[(t * PJ + jgrp) * NB + b0 + tid] = s;
        }
        if (pf) {          // stage next x into LDS
            int b  = tid >> 6;
            int e4 = tid & 63;
            ((float4*)&x_s[b][0])[e4] = xv;
        }
        __syncthreads();   // B4: x_s ready for next iteration
    }
}

__global__ void pz_kernel(const float* __restrict__ part,
                          const float* __restrict__ noise,
                          const float* __restrict__ b_z,
                          float* __restrict__ out)
{
    int idx = blockIdx.x * blockDim.x + threadIdx.x;  // t*64 + b
    if (idx >= TT * NB) return;
    int t = idx >> 6, b = idx & 63;
    float s = b_z[0];
    #pragma unroll
    for (int jg = 0; jg < PJ; ++jg) s += part[(t * PJ + jg) * NB + b];
    float pz = 1.f / (1.f + expf(-s));
    out[idx] = pz;
    out[TT * NB + idx] = (noise[idx] < pz) ? 1.f : 0.f;
}

// One block per batch column: stable compaction of tokens where z==1.
__global__ void compact_kernel(const int* __restrict__ sent,
                               const float* __restrict__ zbuf,
                               float* __restrict__ rat,
                               float* __restrict__ zsz)
{
    __shared__ float rat_s[TT];
    __shared__ int scan_s[256];
    int b = blockIdx.x, tid = threadIdx.x;
    int zloc[8];
    int base = tid * 8;
    int c = 0;
    #pragma unroll
    for (int i = 0; i < 8; ++i) {
        zloc[i] = (zbuf[(base + i) * NB + b] != 0.f) ? 1 : 0;
        c += zloc[i];
    }
    scan_s[tid] = c;
    for (int i = tid; i < TT; i += 256) rat_s[i] = 0.f;
    __syncthreads();
    for (int off = 1; off < 256; off <<= 1) {
        int v = scan_s[tid];
        int add = (tid >= off) ? scan_s[tid - off] : 0;
        __syncthreads();
        scan_s[tid] = v + add;
        __syncthreads();
    }
    int total = scan_s[255];
    int pos = scan_s[tid] - c;  // exclusive prefix
    #pragma unroll
    for (int i = 0; i < 8; ++i) {
        if (zloc[i]) { rat_s[pos] = (float)sent[(base + i) * NB + b]; ++pos; }
    }
    __syncthreads();
    for (int i = tid; i < TT; i += 256) rat[i * NB + b] = rat_s[i];
    if (tid == 0) zsz[b] = (float)total;
}

extern "C" void kernel_launch(void* const* d_in, const int* in_sizes, int n_in,
                              void* d_out, int out_size, void* d_ws, size_t ws_size,
                              hipStream_t stream)
{
    const int*   sent  = (const int*)d_in[0];
    const float* noise = (const float*)d_in[1];
    const float* emb   = (const float*)d_in[2];
    const float* W_ih  = (const float*)d_in[3];
    const float* W_hh  = (const float*)d_in[4];
    const float* b_ih  = (const float*)d_in[5];
    const float* b_hh  = (const float*)d_in[6];
    const float* W_z   = (const float*)d_in[7];
    const float* b_z   = (const float*)d_in[8];
    float* out = (float*)d_out;

    char* ws = (char*)d_ws;
    unsigned long long* hbuf = (unsigned long long*)ws;     // 2*64*256*8 = 256 KB
    float* part = (float*)(ws + 262144);                    // 2048*16*64*4 = 8 MB

    // tags must start != any expected tag (1..2048)
    hipMemsetAsync(hbuf, 0, 2 * NB * HH * sizeof(unsigned long long), stream);

    lstm_kernel<<<256, 256, 0, stream>>>(sent, emb, W_ih, W_hh, b_ih, b_hh, W_z,
                                         hbuf, part);
    pz_kernel<<<(TT * NB) / 256, 256, 0, stream>>>(part, noise, b_z, out);
    compact_kernel<<<NB, 256, 0, stream>>>(sent, out + TT * NB,
                                           out + 2 * TT * NB, out + 3 * TT * NB);
}